// Round 5
// baseline (425.357 us; speedup 1.0000x reference)
//
#include <hip/hip_runtime.h>

constexpr int N_NODES  = 100000;
constexpr int N_EDGES  = 1200000;
constexpr int N_GRAPHS = 1000;
constexpr int DIM      = 64;
constexpr int ODIM     = 32;
constexpr int MAXD     = 10;

constexpr int SCAN_CHUNK = 1024;
constexpr int SCAN_NB    = (N_NODES + SCAN_CHUNK - 1) / SCAN_CHUNK;  // 98

constexpr int NBKT      = 32;                       // ordering buckets: min(deg,31)
constexpr int LIST_PAD  = N_NODES + NBKT * 15;      // 100480: max padded list length
constexpr int CONV_BLK  = LIST_PAD / 16;            // 6280 blocks (16 nodes/block)

// ---------------------------------------------------------------------------
// CSR build step 1: in-degree histogram
// ---------------------------------------------------------------------------
__global__ void deg_hist_kernel(const int* __restrict__ dst, int* __restrict__ deg) {
    int e = blockIdx.x * blockDim.x + threadIdx.x;
    if (e < N_EDGES) atomicAdd(&deg[dst[e]], 1);
}

// ---------------------------------------------------------------------------
// Hierarchical exclusive scan of deg -> rowptr, cursor
// ---------------------------------------------------------------------------
__global__ void scan_partial_kernel(const int* __restrict__ deg, int* __restrict__ partials) {
    __shared__ int red[256];
    int b = blockIdx.x, t = threadIdx.x;
    int base = b * SCAN_CHUNK + t * 4;
    int s = 0;
    if (base < N_NODES) {
        int4 v = *reinterpret_cast<const int4*>(deg + base);
        s = v.x + v.y + v.z + v.w;
    }
    red[t] = s;
    __syncthreads();
    for (int off = 128; off > 0; off >>= 1) {
        if (t < off) red[t] += red[t + off];
        __syncthreads();
    }
    if (t == 0) partials[b] = red[0];
}

__global__ void scan_partials_kernel(const int* __restrict__ partials,
                                     int* __restrict__ blockoff,
                                     int* __restrict__ rowptr) {
    __shared__ int sh[128];
    int t = threadIdx.x;
    int v = (t < SCAN_NB) ? partials[t] : 0;
    sh[t] = v;
    __syncthreads();
    for (int off = 1; off < 128; off <<= 1) {
        int u = (t >= off) ? sh[t - off] : 0;
        __syncthreads();
        sh[t] += u;
        __syncthreads();
    }
    if (t < SCAN_NB) blockoff[t] = sh[t] - v;
    if (t == SCAN_NB - 1) rowptr[N_NODES] = sh[t];
}

__global__ void scan_final_kernel(const int* __restrict__ deg,
                                  const int* __restrict__ blockoff,
                                  int* __restrict__ rowptr,
                                  int* __restrict__ cursor) {
    __shared__ int sh[256];
    int b = blockIdx.x, t = threadIdx.x;
    int base = b * SCAN_CHUNK + t * 4;
    int4 v = make_int4(0, 0, 0, 0);
    if (base < N_NODES) v = *reinterpret_cast<const int4*>(deg + base);
    int s = v.x + v.y + v.z + v.w;
    sh[t] = s;
    __syncthreads();
    for (int off = 1; off < 256; off <<= 1) {
        int u = (t >= off) ? sh[t - off] : 0;
        __syncthreads();
        sh[t] += u;
        __syncthreads();
    }
    if (base < N_NODES) {
        int p0 = sh[t] - s + blockoff[b];
        int p1 = p0 + v.x, p2 = p1 + v.y, p3 = p2 + v.z;
        int4 pr = make_int4(p0, p1, p2, p3);
        *reinterpret_cast<int4*>(rowptr + base) = pr;
        *reinterpret_cast<int4*>(cursor + base) = pr;
    }
}

// ---------------------------------------------------------------------------
// CSR build step 3: bin edges
// ---------------------------------------------------------------------------
__global__ void fill_csr_kernel(const int* __restrict__ src, const int* __restrict__ dst,
                                int* __restrict__ cursor, int* __restrict__ csr) {
    int e = blockIdx.x * blockDim.x + threadIdx.x;
    if (e < N_EDGES) {
        int p = atomicAdd(&cursor[dst[e]], 1);
        csr[p] = src[e];
    }
}

// ---------------------------------------------------------------------------
// Degree buckets: LDS-aggregated 32-bin histogram over key = min(deg, 31)
// ---------------------------------------------------------------------------
__global__ void bucket_hist_kernel(const int* __restrict__ deg, int* __restrict__ gcount) {
    __shared__ int lh[NBKT];
    int t = threadIdx.x;
    if (t < NBKT) lh[t] = 0;
    __syncthreads();
    int i = blockIdx.x * 256 + t;
    if (i < N_NODES) {
        int k = min(deg[i], NBKT - 1);
        atomicAdd(&lh[k], 1);
    }
    __syncthreads();
    if (t < NBKT && lh[t]) atomicAdd(&gcount[t], lh[t]);
}

// bucket offsets, padded so each bucket starts on a 16-node block boundary
__global__ void bucket_scan_kernel(const int* __restrict__ gcount,
                                   int* __restrict__ gcur) {
    if (threadIdx.x == 0) {
        int off = 0;
        for (int k = 0; k < NBKT; ++k) {
            gcur[k] = off;
            off += (gcount[k] + 15) & ~15;
        }
    }
}

__global__ void bucket_scatter_kernel(const int* __restrict__ deg,
                                      int* __restrict__ gcur,
                                      int* __restrict__ nodelist) {
    __shared__ int lh[NBKT], lbase[NBKT];
    int t = threadIdx.x;
    if (t < NBKT) lh[t] = 0;
    __syncthreads();
    int i = blockIdx.x * 256 + t;
    int k = 0, r = 0;
    bool valid = (i < N_NODES);
    if (valid) {
        k = min(deg[i], NBKT - 1);
        r = atomicAdd(&lh[k], 1);
    }
    __syncthreads();
    if (t < NBKT && lh[t]) lbase[t] = atomicAdd(&gcur[t], lh[t]);
    __syncthreads();
    if (valid) nodelist[lbase[k] + r] = i;
}

// ---------------------------------------------------------------------------
// Graph node ranges via binary search on sorted batch
// ---------------------------------------------------------------------------
__global__ void graph_bounds_kernel(const int* __restrict__ batch, int* __restrict__ grow) {
    int t = blockIdx.x * blockDim.x + threadIdx.x;
    if (t > N_GRAPHS) return;
    if (t == N_GRAPHS) { grow[t] = N_NODES; return; }
    int lo = 0, hi = N_NODES;
    while (lo < hi) { int mid = (lo + hi) >> 1; if (batch[mid] < t) lo = mid + 1; else hi = mid; }
    grow[t] = lo;
}

// ---------------------------------------------------------------------------
// Bucketed fused gather + MFConv: 16 nodes/block (16 lanes, float4/lane each),
// all nodes in a block share the same clamped degree -> uniform weights.
// LDS staging padded to 68 floats/row: broadcast reads hit 4 distinct banks.
// ---------------------------------------------------------------------------
template <int RELU>
__global__ __launch_bounds__(256) void conv_bkt_kernel(const float* __restrict__ xin,
                                                       const int* __restrict__ rowptr,
                                                       const int* __restrict__ csr,
                                                       const int* __restrict__ nodelist,
                                                       const float* __restrict__ Wl,
                                                       const float* __restrict__ bl,
                                                       const float* __restrict__ Wr,
                                                       float* __restrict__ out) {
    __shared__ float lds_h[16][DIM + 4];
    __shared__ float lds_x[16][DIM + 4];
    int grp = threadIdx.x >> 4;
    int q   = threadIdx.x & 15;
    int base = blockIdx.x * 16;

    int node0 = nodelist[base];
    if (node0 < 0) return;               // fully-padded / out-of-range block
    int node = nodelist[base + grp];
    bool valid = (node >= 0);

    int beg = 0, end = 0;
    if (valid) { beg = rowptr[node]; end = rowptr[node + 1]; }

    float4 xv = make_float4(0.f, 0.f, 0.f, 0.f);
    if (valid) xv = *reinterpret_cast<const float4*>(xin + (size_t)node * DIM + q * 4);
    float4 hs = make_float4(0.f, 0.f, 0.f, 0.f);

    int e = beg;
    for (; e + 8 <= end; e += 8) {
        int s0 = csr[e + 0], s1 = csr[e + 1], s2 = csr[e + 2], s3 = csr[e + 3];
        int s4 = csr[e + 4], s5 = csr[e + 5], s6 = csr[e + 6], s7 = csr[e + 7];
        float4 a = *reinterpret_cast<const float4*>(xin + (size_t)s0 * DIM + q * 4);
        float4 b = *reinterpret_cast<const float4*>(xin + (size_t)s1 * DIM + q * 4);
        float4 c = *reinterpret_cast<const float4*>(xin + (size_t)s2 * DIM + q * 4);
        float4 d = *reinterpret_cast<const float4*>(xin + (size_t)s3 * DIM + q * 4);
        float4 f = *reinterpret_cast<const float4*>(xin + (size_t)s4 * DIM + q * 4);
        float4 g = *reinterpret_cast<const float4*>(xin + (size_t)s5 * DIM + q * 4);
        float4 h = *reinterpret_cast<const float4*>(xin + (size_t)s6 * DIM + q * 4);
        float4 k = *reinterpret_cast<const float4*>(xin + (size_t)s7 * DIM + q * 4);
        hs.x += (a.x + b.x) + (c.x + d.x) + (f.x + g.x) + (h.x + k.x);
        hs.y += (a.y + b.y) + (c.y + d.y) + (f.y + g.y) + (h.y + k.y);
        hs.z += (a.z + b.z) + (c.z + d.z) + (f.z + g.z) + (h.z + k.z);
        hs.w += (a.w + b.w) + (c.w + d.w) + (f.w + g.w) + (h.w + k.w);
    }
    for (; e + 4 <= end; e += 4) {
        int s0 = csr[e + 0], s1 = csr[e + 1], s2 = csr[e + 2], s3 = csr[e + 3];
        float4 a = *reinterpret_cast<const float4*>(xin + (size_t)s0 * DIM + q * 4);
        float4 b = *reinterpret_cast<const float4*>(xin + (size_t)s1 * DIM + q * 4);
        float4 c = *reinterpret_cast<const float4*>(xin + (size_t)s2 * DIM + q * 4);
        float4 d = *reinterpret_cast<const float4*>(xin + (size_t)s3 * DIM + q * 4);
        hs.x += (a.x + b.x) + (c.x + d.x);
        hs.y += (a.y + b.y) + (c.y + d.y);
        hs.z += (a.z + b.z) + (c.z + d.z);
        hs.w += (a.w + b.w) + (c.w + d.w);
    }
    for (; e < end; ++e) {
        int s = csr[e];
        float4 a = *reinterpret_cast<const float4*>(xin + (size_t)s * DIM + q * 4);
        hs.x += a.x; hs.y += a.y; hs.z += a.z; hs.w += a.w;
    }

    *reinterpret_cast<float4*>(&lds_h[grp][q * 4]) = hs;
    *reinterpret_cast<float4*>(&lds_x[grp][q * 4]) = xv;
    __syncthreads();

    // uniform weight index for the whole block
    int d0 = rowptr[node0 + 1] - rowptr[node0];
    d0 = d0 > MAXD ? MAXD : d0;
    const float* wl = Wl + (size_t)d0 * DIM * DIM + q * 4;
    const float* wr = Wr + (size_t)d0 * DIM * DIM + q * 4;
    float4 acc = *reinterpret_cast<const float4*>(bl + d0 * DIM + q * 4);

#pragma unroll 8
    for (int i = 0; i < DIM; ++i) {
        float h  = lds_h[grp][i];
        float xx = lds_x[grp][i];
        float4 wlv = *reinterpret_cast<const float4*>(wl + i * DIM);
        float4 wrv = *reinterpret_cast<const float4*>(wr + i * DIM);
        acc.x += h * wlv.x + xx * wrv.x;
        acc.y += h * wlv.y + xx * wrv.y;
        acc.z += h * wlv.z + xx * wrv.z;
        acc.w += h * wlv.w + xx * wrv.w;
    }
    if (RELU) {
        acc.x = fmaxf(acc.x, 0.f); acc.y = fmaxf(acc.y, 0.f);
        acc.z = fmaxf(acc.z, 0.f); acc.w = fmaxf(acc.w, 0.f);
    }
    if (valid)
        *reinterpret_cast<float4*>(out + (size_t)node * DIM + q * 4) = acc;
}

// ---------------------------------------------------------------------------
// global_add_pool of relu(emb)
// ---------------------------------------------------------------------------
__global__ void pool_kernel(const float* __restrict__ emb,
                            const int* __restrict__ grow,
                            float* __restrict__ g) {
    __shared__ float red[4][DIM];
    int gi = blockIdx.x;
    int w = threadIdx.x >> 6;
    int lane = threadIdx.x & 63;
    int beg = grow[gi], end = grow[gi + 1];
    float acc = 0.f;
    for (int n = beg + w; n < end; n += 4)
        acc += fmaxf(emb[(size_t)n * DIM + lane], 0.f);
    red[w][lane] = acc;
    __syncthreads();
    if (w == 0) {
        g[(size_t)gi * DIM + lane] = red[0][lane] + red[1][lane] + red[2][lane] + red[3][lane];
    }
}

// ---------------------------------------------------------------------------
// Head
// ---------------------------------------------------------------------------
__global__ void head_kernel(const float* __restrict__ g,
                            const float* __restrict__ W1,
                            const float* __restrict__ b1,
                            const float* __restrict__ W2,
                            const float* __restrict__ b2,
                            float* __restrict__ pred) {
    __shared__ float hid[DIM];
    int gi = blockIdx.x;
    int o = threadIdx.x;
    const float* gv = g + (size_t)gi * DIM;
    float acc = b1[o];
#pragma unroll 8
    for (int i = 0; i < DIM; ++i) acc += gv[i] * W1[i * DIM + o];
    hid[o] = acc;
    __syncthreads();
    if (o < ODIM) {
        float p = b2[o];
#pragma unroll 8
        for (int i = 0; i < DIM; ++i) p += hid[i] * W2[i * ODIM + o];
        pred[(size_t)gi * ODIM + o] = p;
    }
}

extern "C" void kernel_launch(void* const* d_in, const int* in_sizes, int n_in,
                              void* d_out, int out_size, void* d_ws, size_t ws_size,
                              hipStream_t stream) {
    const float* x    = (const float*)d_in[0];
    const int* eidx   = (const int*)d_in[1];
    const int* src    = eidx;
    const int* dst    = eidx + N_EDGES;
    const int* batch  = (const int*)d_in[2];
    const float* Wl1  = (const float*)d_in[4];
    const float* bl1  = (const float*)d_in[5];
    const float* Wr1  = (const float*)d_in[6];
    const float* Wl2  = (const float*)d_in[7];
    const float* bl2  = (const float*)d_in[8];
    const float* Wr2  = (const float*)d_in[9];
    const float* W1   = (const float*)d_in[10];
    const float* b1   = (const float*)d_in[11];
    const float* W2   = (const float*)d_in[12];
    const float* b2   = (const float*)d_in[13];

    float* emb  = (float*)d_out;                          // [N_NODES, 64]
    float* pred = (float*)d_out + (size_t)N_NODES * DIM;  // [N_GRAPHS, 32]

    // Workspace layout (all counts multiples of 4 ints -> 16B alignment kept)
    int* deg      = (int*)d_ws;                  // [100000]
    int* rowptr   = deg + N_NODES;               // [100004]
    int* cursor   = rowptr + N_NODES + 4;        // [100000]
    int* csr      = cursor + N_NODES;            // [1200000]
    int* grow     = csr + N_EDGES;               // [1004]
    int* partials = grow + 1004;                 // [100]
    int* blockoff = partials + 100;              // [100]
    int* gcount   = blockoff + 100;              // [32]
    int* gcur     = gcount + NBKT;               // [32]
    int* nodelist = gcur + NBKT;                 // [100480]
    float* hrelu  = (float*)(nodelist + LIST_PAD);       // [N,64]
    float* g      = hrelu + (size_t)N_NODES * DIM;       // [G,64]

    hipMemsetAsync(deg, 0, (size_t)N_NODES * sizeof(int), stream);
    hipMemsetAsync(gcount, 0, NBKT * sizeof(int), stream);
    hipMemsetAsync(nodelist, 0xFF, (size_t)LIST_PAD * sizeof(int), stream);

    deg_hist_kernel<<<(N_EDGES + 255) / 256, 256, 0, stream>>>(dst, deg);
    scan_partial_kernel<<<SCAN_NB, 256, 0, stream>>>(deg, partials);
    scan_partials_kernel<<<1, 128, 0, stream>>>(partials, blockoff, rowptr);
    scan_final_kernel<<<SCAN_NB, 256, 0, stream>>>(deg, blockoff, rowptr, cursor);
    fill_csr_kernel<<<(N_EDGES + 255) / 256, 256, 0, stream>>>(src, dst, cursor, csr);

    bucket_hist_kernel<<<(N_NODES + 255) / 256, 256, 0, stream>>>(deg, gcount);
    bucket_scan_kernel<<<1, 64, 0, stream>>>(gcount, gcur);
    bucket_scatter_kernel<<<(N_NODES + 255) / 256, 256, 0, stream>>>(deg, gcur, nodelist);

    graph_bounds_kernel<<<(N_GRAPHS + 1 + 255) / 256, 256, 0, stream>>>(batch, grow);

    // conv1: gather + matvec + relu -> hrelu
    conv_bkt_kernel<1><<<CONV_BLK, 256, 0, stream>>>(x, rowptr, csr, nodelist,
                                                     Wl1, bl1, Wr1, hrelu);
    // conv2: gather + matvec -> emb
    conv_bkt_kernel<0><<<CONV_BLK, 256, 0, stream>>>(hrelu, rowptr, csr, nodelist,
                                                     Wl2, bl2, Wr2, emb);
    // pool relu(emb) per graph
    pool_kernel<<<N_GRAPHS, 256, 0, stream>>>(emb, grow, g);
    // head
    head_kernel<<<N_GRAPHS, DIM, 0, stream>>>(g, W1, b1, W2, b2, pred);
}

// Round 6
// 362.749 us; speedup vs baseline: 1.1726x; 1.1726x over previous
//
#include <hip/hip_runtime.h>

constexpr int N_NODES  = 100000;
constexpr int N_EDGES  = 1200000;
constexpr int N_GRAPHS = 1000;
constexpr int DIM      = 64;
constexpr int ODIM     = 32;
constexpr int MAXD     = 10;

constexpr int SCAN_CHUNK = 1024;
constexpr int SCAN_NB    = (N_NODES + SCAN_CHUNK - 1) / SCAN_CHUNK;  // 98

constexpr int NBKT     = 32;                        // buckets: min(deg,31)
constexpr int BPAD     = 32;                        // nodes per conv block
constexpr int LIST_PAD = N_NODES + NBKT * (BPAD - 1);  // 100992
constexpr int CONV_BLK = LIST_PAD / BPAD;           // 3156

// ---------------- bf16 helpers (RNE pack, trivial unpack) -------------------
__device__ __forceinline__ unsigned short f2bf(float f) {
    unsigned u = __float_as_uint(f);
    u = (u + 0x7fffu + ((u >> 16) & 1u)) >> 16;
    return (unsigned short)u;
}
__device__ __forceinline__ float bflo(int u) {   // elem at low 16 bits
    return __uint_as_float((unsigned)u << 16);
}
__device__ __forceinline__ float bfhi(int u) {   // elem at high 16 bits
    return __uint_as_float((unsigned)u & 0xffff0000u);
}

// ---------------------------------------------------------------------------
// CSR build step 1: in-degree histogram
// ---------------------------------------------------------------------------
__global__ void deg_hist_kernel(const int* __restrict__ dst, int* __restrict__ deg) {
    int e = blockIdx.x * blockDim.x + threadIdx.x;
    if (e < N_EDGES) atomicAdd(&deg[dst[e]], 1);
}

// ---------------------------------------------------------------------------
// Hierarchical exclusive scan of deg -> rowptr, cursor
// ---------------------------------------------------------------------------
__global__ void scan_partial_kernel(const int* __restrict__ deg, int* __restrict__ partials) {
    __shared__ int red[256];
    int b = blockIdx.x, t = threadIdx.x;
    int base = b * SCAN_CHUNK + t * 4;
    int s = 0;
    if (base < N_NODES) {
        int4 v = *reinterpret_cast<const int4*>(deg + base);
        s = v.x + v.y + v.z + v.w;
    }
    red[t] = s;
    __syncthreads();
    for (int off = 128; off > 0; off >>= 1) {
        if (t < off) red[t] += red[t + off];
        __syncthreads();
    }
    if (t == 0) partials[b] = red[0];
}

__global__ void scan_partials_kernel(const int* __restrict__ partials,
                                     int* __restrict__ blockoff,
                                     int* __restrict__ rowptr) {
    __shared__ int sh[128];
    int t = threadIdx.x;
    int v = (t < SCAN_NB) ? partials[t] : 0;
    sh[t] = v;
    __syncthreads();
    for (int off = 1; off < 128; off <<= 1) {
        int u = (t >= off) ? sh[t - off] : 0;
        __syncthreads();
        sh[t] += u;
        __syncthreads();
    }
    if (t < SCAN_NB) blockoff[t] = sh[t] - v;
    if (t == SCAN_NB - 1) rowptr[N_NODES] = sh[t];
}

__global__ void scan_final_kernel(const int* __restrict__ deg,
                                  const int* __restrict__ blockoff,
                                  int* __restrict__ rowptr,
                                  int* __restrict__ cursor) {
    __shared__ int sh[256];
    int b = blockIdx.x, t = threadIdx.x;
    int base = b * SCAN_CHUNK + t * 4;
    int4 v = make_int4(0, 0, 0, 0);
    if (base < N_NODES) v = *reinterpret_cast<const int4*>(deg + base);
    int s = v.x + v.y + v.z + v.w;
    sh[t] = s;
    __syncthreads();
    for (int off = 1; off < 256; off <<= 1) {
        int u = (t >= off) ? sh[t - off] : 0;
        __syncthreads();
        sh[t] += u;
        __syncthreads();
    }
    if (base < N_NODES) {
        int p0 = sh[t] - s + blockoff[b];
        int p1 = p0 + v.x, p2 = p1 + v.y, p3 = p2 + v.z;
        int4 pr = make_int4(p0, p1, p2, p3);
        *reinterpret_cast<int4*>(rowptr + base) = pr;
        *reinterpret_cast<int4*>(cursor + base) = pr;
    }
}

// ---------------------------------------------------------------------------
// CSR build step 3: bin edges
// ---------------------------------------------------------------------------
__global__ void fill_csr_kernel(const int* __restrict__ src, const int* __restrict__ dst,
                                int* __restrict__ cursor, int* __restrict__ csr) {
    int e = blockIdx.x * blockDim.x + threadIdx.x;
    if (e < N_EDGES) {
        int p = atomicAdd(&cursor[dst[e]], 1);
        csr[p] = src[e];
    }
}

// ---------------------------------------------------------------------------
// Degree buckets (key = min(deg,31)); padded to BPAD-node block boundaries
// ---------------------------------------------------------------------------
__global__ void bucket_hist_kernel(const int* __restrict__ deg, int* __restrict__ gcount) {
    __shared__ int lh[NBKT];
    int t = threadIdx.x;
    if (t < NBKT) lh[t] = 0;
    __syncthreads();
    int i = blockIdx.x * 256 + t;
    if (i < N_NODES) {
        int k = min(deg[i], NBKT - 1);
        atomicAdd(&lh[k], 1);
    }
    __syncthreads();
    if (t < NBKT && lh[t]) atomicAdd(&gcount[t], lh[t]);
}

__global__ void bucket_scan_kernel(const int* __restrict__ gcount,
                                   int* __restrict__ gcur) {
    if (threadIdx.x == 0) {
        int off = 0;
        for (int k = 0; k < NBKT; ++k) {
            gcur[k] = off;
            off += (gcount[k] + BPAD - 1) & ~(BPAD - 1);
        }
    }
}

__global__ void bucket_scatter_kernel(const int* __restrict__ deg,
                                      int* __restrict__ gcur,
                                      int* __restrict__ nodelist) {
    __shared__ int lh[NBKT], lbase[NBKT];
    int t = threadIdx.x;
    if (t < NBKT) lh[t] = 0;
    __syncthreads();
    int i = blockIdx.x * 256 + t;
    int k = 0, r = 0;
    bool valid = (i < N_NODES);
    if (valid) {
        k = min(deg[i], NBKT - 1);
        r = atomicAdd(&lh[k], 1);
    }
    __syncthreads();
    if (t < NBKT && lh[t]) lbase[t] = atomicAdd(&gcur[t], lh[t]);
    __syncthreads();
    if (valid) nodelist[lbase[k] + r] = i;
}

// ---------------------------------------------------------------------------
// Graph node ranges via binary search on sorted batch
// ---------------------------------------------------------------------------
__global__ void graph_bounds_kernel(const int* __restrict__ batch, int* __restrict__ grow) {
    int t = blockIdx.x * blockDim.x + threadIdx.x;
    if (t > N_GRAPHS) return;
    if (t == N_GRAPHS) { grow[t] = N_NODES; return; }
    int lo = 0, hi = N_NODES;
    while (lo < hi) { int mid = (lo + hi) >> 1; if (batch[mid] < t) lo = mid + 1; else hi = mid; }
    grow[t] = lo;
}

// ---------------------------------------------------------------------------
// f32 -> bf16 row conversion (for gather tables)
// ---------------------------------------------------------------------------
__global__ void f32_to_bf16_kernel(const float* __restrict__ in,
                                   unsigned short* __restrict__ out) {
    int i = (blockIdx.x * blockDim.x + threadIdx.x) * 4;   // N*DIM % 4 == 0
    if (i < N_NODES * DIM) {
        float4 v = *reinterpret_cast<const float4*>(in + i);
        ushort4 o;
        o.x = f2bf(v.x); o.y = f2bf(v.y); o.z = f2bf(v.z); o.w = f2bf(v.w);
        *reinterpret_cast<ushort4*>(out + i) = o;
    }
}

// ---------------------------------------------------------------------------
// Bucketed fused gather(bf16) + MFConv.
// Gather phase: 32 groups x 8 lanes; group = one node; lane q holds dims q*8..q*8+7
//   (one int4 = 16B = 8 bf16 per lane; one wave-instr gathers 8 edges).
// Matvec phase: 16 groups x 16 lanes; group handles 2 nodes sharing weight loads
//   (weight index uniform per block: exact-degree buckets; deg>=31 all clamp to 10).
// OUTMODE 0: write f32 rows to outf.  OUTMODE 1: relu + write bf16 rows to outb.
// ---------------------------------------------------------------------------
template <int OUTMODE>
__global__ __launch_bounds__(256) void conv_bf16_kernel(
        const unsigned short* __restrict__ xbf,
        const int* __restrict__ rowptr,
        const int* __restrict__ csr,
        const int* __restrict__ nodelist,
        const float* __restrict__ Wl,
        const float* __restrict__ bl,
        const float* __restrict__ Wr,
        float* __restrict__ outf,
        unsigned short* __restrict__ outb) {
    __shared__ float lds_h[BPAD][DIM + 4];
    __shared__ float lds_x[BPAD][DIM + 4];
    __shared__ int s_node[BPAD];
    __shared__ int s_d0;

    int base = blockIdx.x * BPAD;
    int node0 = nodelist[base];
    if (node0 < 0) return;                 // fully-padded tail block

    // ---- gather phase: 8 lanes per node ----
    int grp = threadIdx.x >> 3;            // 0..31  (node slot)
    int q   = threadIdx.x & 7;             // dim octet
    int node = nodelist[base + grp];
    bool valid = (node >= 0);

    int beg = 0, end = 0;
    if (valid) { beg = rowptr[node]; end = rowptr[node + 1]; }

    if (threadIdx.x == 0) s_d0 = min(end - beg, MAXD);
    if (q == 0) s_node[grp] = node;

    float hs[8];
#pragma unroll
    for (int j = 0; j < 8; ++j) hs[j] = 0.f;

    int e = beg;
    for (; e + 8 <= end; e += 8) {
        int s0 = csr[e + 0], s1 = csr[e + 1], s2 = csr[e + 2], s3 = csr[e + 3];
        int s4 = csr[e + 4], s5 = csr[e + 5], s6 = csr[e + 6], s7 = csr[e + 7];
        int4 a0 = *reinterpret_cast<const int4*>(xbf + (size_t)s0 * DIM + q * 8);
        int4 a1 = *reinterpret_cast<const int4*>(xbf + (size_t)s1 * DIM + q * 8);
        int4 a2 = *reinterpret_cast<const int4*>(xbf + (size_t)s2 * DIM + q * 8);
        int4 a3 = *reinterpret_cast<const int4*>(xbf + (size_t)s3 * DIM + q * 8);
        int4 a4 = *reinterpret_cast<const int4*>(xbf + (size_t)s4 * DIM + q * 8);
        int4 a5 = *reinterpret_cast<const int4*>(xbf + (size_t)s5 * DIM + q * 8);
        int4 a6 = *reinterpret_cast<const int4*>(xbf + (size_t)s6 * DIM + q * 8);
        int4 a7 = *reinterpret_cast<const int4*>(xbf + (size_t)s7 * DIM + q * 8);
#define BFACC(a) \
        hs[0] += bflo(a.x); hs[1] += bfhi(a.x); \
        hs[2] += bflo(a.y); hs[3] += bfhi(a.y); \
        hs[4] += bflo(a.z); hs[5] += bfhi(a.z); \
        hs[6] += bflo(a.w); hs[7] += bfhi(a.w);
        BFACC(a0) BFACC(a1) BFACC(a2) BFACC(a3)
        BFACC(a4) BFACC(a5) BFACC(a6) BFACC(a7)
    }
    for (; e + 4 <= end; e += 4) {
        int s0 = csr[e + 0], s1 = csr[e + 1], s2 = csr[e + 2], s3 = csr[e + 3];
        int4 a0 = *reinterpret_cast<const int4*>(xbf + (size_t)s0 * DIM + q * 8);
        int4 a1 = *reinterpret_cast<const int4*>(xbf + (size_t)s1 * DIM + q * 8);
        int4 a2 = *reinterpret_cast<const int4*>(xbf + (size_t)s2 * DIM + q * 8);
        int4 a3 = *reinterpret_cast<const int4*>(xbf + (size_t)s3 * DIM + q * 8);
        BFACC(a0) BFACC(a1) BFACC(a2) BFACC(a3)
    }
    for (; e < end; ++e) {
        int s = csr[e];
        int4 a = *reinterpret_cast<const int4*>(xbf + (size_t)s * DIM + q * 8);
        BFACC(a)
    }
#undef BFACC

    // self row
    float xv[8];
    if (valid) {
        int4 a = *reinterpret_cast<const int4*>(xbf + (size_t)node * DIM + q * 8);
        xv[0] = bflo(a.x); xv[1] = bfhi(a.x);
        xv[2] = bflo(a.y); xv[3] = bfhi(a.y);
        xv[4] = bflo(a.z); xv[5] = bfhi(a.z);
        xv[6] = bflo(a.w); xv[7] = bfhi(a.w);
    } else {
#pragma unroll
        for (int j = 0; j < 8; ++j) xv[j] = 0.f;
    }

    *reinterpret_cast<float4*>(&lds_h[grp][q * 8 + 0]) = make_float4(hs[0], hs[1], hs[2], hs[3]);
    *reinterpret_cast<float4*>(&lds_h[grp][q * 8 + 4]) = make_float4(hs[4], hs[5], hs[6], hs[7]);
    *reinterpret_cast<float4*>(&lds_x[grp][q * 8 + 0]) = make_float4(xv[0], xv[1], xv[2], xv[3]);
    *reinterpret_cast<float4*>(&lds_x[grp][q * 8 + 4]) = make_float4(xv[4], xv[5], xv[6], xv[7]);
    __syncthreads();

    // ---- matvec phase: 16 lanes per node, 2 nodes per group, shared weights ----
    int mgrp = threadIdx.x >> 4;           // 0..15 -> slots mgrp, mgrp+16
    int mq   = threadIdx.x & 15;
    int d0 = s_d0;
    const float* wl = Wl + (size_t)d0 * DIM * DIM + mq * 4;
    const float* wr = Wr + (size_t)d0 * DIM * DIM + mq * 4;
    float4 accA = *reinterpret_cast<const float4*>(bl + d0 * DIM + mq * 4);
    float4 accB = accA;

#pragma unroll 8
    for (int i = 0; i < DIM; ++i) {
        float4 wlv = *reinterpret_cast<const float4*>(wl + i * DIM);
        float4 wrv = *reinterpret_cast<const float4*>(wr + i * DIM);
        float hA = lds_h[mgrp][i],      xA = lds_x[mgrp][i];
        float hB = lds_h[mgrp + 16][i], xB = lds_x[mgrp + 16][i];
        accA.x += hA * wlv.x + xA * wrv.x;
        accA.y += hA * wlv.y + xA * wrv.y;
        accA.z += hA * wlv.z + xA * wrv.z;
        accA.w += hA * wlv.w + xA * wrv.w;
        accB.x += hB * wlv.x + xB * wrv.x;
        accB.y += hB * wlv.y + xB * wrv.y;
        accB.z += hB * wlv.z + xB * wrv.z;
        accB.w += hB * wlv.w + xB * wrv.w;
    }

    int nodeA = s_node[mgrp];
    int nodeB = s_node[mgrp + 16];
    if (OUTMODE == 0) {
        if (nodeA >= 0)
            *reinterpret_cast<float4*>(outf + (size_t)nodeA * DIM + mq * 4) = accA;
        if (nodeB >= 0)
            *reinterpret_cast<float4*>(outf + (size_t)nodeB * DIM + mq * 4) = accB;
    } else {
        if (nodeA >= 0) {
            ushort4 o;
            o.x = f2bf(fmaxf(accA.x, 0.f)); o.y = f2bf(fmaxf(accA.y, 0.f));
            o.z = f2bf(fmaxf(accA.z, 0.f)); o.w = f2bf(fmaxf(accA.w, 0.f));
            *reinterpret_cast<ushort4*>(outb + (size_t)nodeA * DIM + mq * 4) = o;
        }
        if (nodeB >= 0) {
            ushort4 o;
            o.x = f2bf(fmaxf(accB.x, 0.f)); o.y = f2bf(fmaxf(accB.y, 0.f));
            o.z = f2bf(fmaxf(accB.z, 0.f)); o.w = f2bf(fmaxf(accB.w, 0.f));
            *reinterpret_cast<ushort4*>(outb + (size_t)nodeB * DIM + mq * 4) = o;
        }
    }
}

// ---------------------------------------------------------------------------
// global_add_pool of relu(emb)
// ---------------------------------------------------------------------------
__global__ void pool_kernel(const float* __restrict__ emb,
                            const int* __restrict__ grow,
                            float* __restrict__ g) {
    __shared__ float red[4][DIM];
    int gi = blockIdx.x;
    int w = threadIdx.x >> 6;
    int lane = threadIdx.x & 63;
    int beg = grow[gi], end = grow[gi + 1];
    float acc = 0.f;
    for (int n = beg + w; n < end; n += 4)
        acc += fmaxf(emb[(size_t)n * DIM + lane], 0.f);
    red[w][lane] = acc;
    __syncthreads();
    if (w == 0) {
        g[(size_t)gi * DIM + lane] = red[0][lane] + red[1][lane] + red[2][lane] + red[3][lane];
    }
}

// ---------------------------------------------------------------------------
// Head
// ---------------------------------------------------------------------------
__global__ void head_kernel(const float* __restrict__ g,
                            const float* __restrict__ W1,
                            const float* __restrict__ b1,
                            const float* __restrict__ W2,
                            const float* __restrict__ b2,
                            float* __restrict__ pred) {
    __shared__ float hid[DIM];
    int gi = blockIdx.x;
    int o = threadIdx.x;
    const float* gv = g + (size_t)gi * DIM;
    float acc = b1[o];
#pragma unroll 8
    for (int i = 0; i < DIM; ++i) acc += gv[i] * W1[i * DIM + o];
    hid[o] = acc;
    __syncthreads();
    if (o < ODIM) {
        float p = b2[o];
#pragma unroll 8
        for (int i = 0; i < DIM; ++i) p += hid[i] * W2[i * ODIM + o];
        pred[(size_t)gi * ODIM + o] = p;
    }
}

extern "C" void kernel_launch(void* const* d_in, const int* in_sizes, int n_in,
                              void* d_out, int out_size, void* d_ws, size_t ws_size,
                              hipStream_t stream) {
    const float* x    = (const float*)d_in[0];
    const int* eidx   = (const int*)d_in[1];
    const int* src    = eidx;
    const int* dst    = eidx + N_EDGES;
    const int* batch  = (const int*)d_in[2];
    const float* Wl1  = (const float*)d_in[4];
    const float* bl1  = (const float*)d_in[5];
    const float* Wr1  = (const float*)d_in[6];
    const float* Wl2  = (const float*)d_in[7];
    const float* bl2  = (const float*)d_in[8];
    const float* Wr2  = (const float*)d_in[9];
    const float* W1   = (const float*)d_in[10];
    const float* b1   = (const float*)d_in[11];
    const float* W2   = (const float*)d_in[12];
    const float* b2   = (const float*)d_in[13];

    float* emb  = (float*)d_out;                          // [N_NODES, 64]
    float* pred = (float*)d_out + (size_t)N_NODES * DIM;  // [N_GRAPHS, 32]

    // Workspace layout (int counts all multiples of 4 -> 16B alignment kept)
    int* deg      = (int*)d_ws;                  // [100000]
    int* rowptr   = deg + N_NODES;               // [100004]
    int* cursor   = rowptr + N_NODES + 4;        // [100000]
    int* csr      = cursor + N_NODES;            // [1200000]
    int* grow     = csr + N_EDGES;               // [1004]
    int* partials = grow + 1004;                 // [100]
    int* blockoff = partials + 100;              // [100]
    int* gcount   = blockoff + 100;              // [32]
    int* gcur     = gcount + NBKT;               // [32]
    int* nodelist = gcur + NBKT;                 // [100992]
    unsigned short* xbf = (unsigned short*)(nodelist + LIST_PAD);  // [N*64] bf16
    unsigned short* hbf = xbf + (size_t)N_NODES * DIM;             // [N*64] bf16
    float* g = (float*)(hbf + (size_t)N_NODES * DIM);              // [G,64]

    hipMemsetAsync(deg, 0, (size_t)N_NODES * sizeof(int), stream);
    hipMemsetAsync(gcount, 0, NBKT * sizeof(int), stream);
    hipMemsetAsync(nodelist, 0xFF, (size_t)LIST_PAD * sizeof(int), stream);

    deg_hist_kernel<<<(N_EDGES + 255) / 256, 256, 0, stream>>>(dst, deg);
    scan_partial_kernel<<<SCAN_NB, 256, 0, stream>>>(deg, partials);
    scan_partials_kernel<<<1, 128, 0, stream>>>(partials, blockoff, rowptr);
    scan_final_kernel<<<SCAN_NB, 256, 0, stream>>>(deg, blockoff, rowptr, cursor);
    fill_csr_kernel<<<(N_EDGES + 255) / 256, 256, 0, stream>>>(src, dst, cursor, csr);

    bucket_hist_kernel<<<(N_NODES + 255) / 256, 256, 0, stream>>>(deg, gcount);
    bucket_scan_kernel<<<1, 64, 0, stream>>>(gcount, gcur);
    bucket_scatter_kernel<<<(N_NODES + 255) / 256, 256, 0, stream>>>(deg, gcur, nodelist);

    graph_bounds_kernel<<<(N_GRAPHS + 1 + 255) / 256, 256, 0, stream>>>(batch, grow);

    // bf16 copy of x for the conv1 gather table
    f32_to_bf16_kernel<<<(N_NODES * DIM / 4 + 255) / 256, 256, 0, stream>>>(x, xbf);

    // conv1: bf16 gather + matvec + relu -> hbf (bf16 rows for conv2)
    conv_bf16_kernel<1><<<CONV_BLK, 256, 0, stream>>>(xbf, rowptr, csr, nodelist,
                                                      Wl1, bl1, Wr1, nullptr, hbf);
    // conv2: bf16 gather + matvec -> emb (f32, pre-activation output)
    conv_bf16_kernel<0><<<CONV_BLK, 256, 0, stream>>>(hbf, rowptr, csr, nodelist,
                                                      Wl2, bl2, Wr2, emb, nullptr);
    // pool relu(emb) per graph
    pool_kernel<<<N_GRAPHS, 256, 0, stream>>>(emb, grow, g);
    // head
    head_kernel<<<N_GRAPHS, DIM, 0, stream>>>(g, W1, b1, W2, b2, pred);
}

// Round 7
// 358.925 us; speedup vs baseline: 1.1851x; 1.0107x over previous
//
#include <hip/hip_runtime.h>

constexpr int N_NODES  = 100000;
constexpr int N_EDGES  = 1200000;
constexpr int N_GRAPHS = 1000;
constexpr int DIM      = 64;
constexpr int ODIM     = 32;
constexpr int MAXD     = 10;

constexpr int SCAN_CHUNK = 1024;
constexpr int SCAN_NB    = (N_NODES + SCAN_CHUNK - 1) / SCAN_CHUNK;  // 98

constexpr int NBKT     = 32;                        // buckets: min(deg,31)
constexpr int BPAD     = 32;                        // nodes per conv block
constexpr int LIST_PAD = N_NODES + NBKT * (BPAD - 1);  // 100992
constexpr int CONV_BLK = LIST_PAD / BPAD;           // 3156

// ---------------- bf16 helpers (RNE pack, trivial unpack) -------------------
__device__ __forceinline__ unsigned short f2bf(float f) {
    unsigned u = __float_as_uint(f);
    u = (u + 0x7fffu + ((u >> 16) & 1u)) >> 16;
    return (unsigned short)u;
}
__device__ __forceinline__ float bflo(int u) {
    return __uint_as_float((unsigned)u << 16);
}
__device__ __forceinline__ float bfhi(int u) {
    return __uint_as_float((unsigned)u & 0xffff0000u);
}

// ---------------------------------------------------------------------------
// Fused init: deg=0, gcount=0, nodelist=-1  (replaces 3 memsets)
// ---------------------------------------------------------------------------
__global__ void init_kernel(int* __restrict__ deg, int* __restrict__ gcount,
                            int* __restrict__ nodelist) {
    int i = blockIdx.x * 256 + threadIdx.x;
    if (i < N_NODES) deg[i] = 0;
    if (i < LIST_PAD) nodelist[i] = -1;
    if (i < NBKT) gcount[i] = 0;
}

// ---------------------------------------------------------------------------
// In-degree histogram
// ---------------------------------------------------------------------------
__global__ void deg_hist_kernel(const int* __restrict__ dst, int* __restrict__ deg) {
    int e = blockIdx.x * blockDim.x + threadIdx.x;
    if (e < N_EDGES) atomicAdd(&deg[dst[e]], 1);
}

// ---------------------------------------------------------------------------
// Scan phase 1 (per-block partial sums) + fused degree-bucket histogram
// ---------------------------------------------------------------------------
__global__ void scan_partial_kernel(const int* __restrict__ deg,
                                    int* __restrict__ partials,
                                    int* __restrict__ gcount) {
    __shared__ int red[256];
    __shared__ int lh[NBKT];
    int b = blockIdx.x, t = threadIdx.x;
    if (t < NBKT) lh[t] = 0;
    int base = b * SCAN_CHUNK + t * 4;
    int4 v = make_int4(0, 0, 0, 0);
    int s = 0;
    if (base < N_NODES) {
        v = *reinterpret_cast<const int4*>(deg + base);
        s = v.x + v.y + v.z + v.w;
    }
    red[t] = s;
    __syncthreads();
    for (int off = 128; off > 0; off >>= 1) {
        if (t < off) red[t] += red[t + off];
        __syncthreads();
    }
    if (base < N_NODES) {
        atomicAdd(&lh[min(v.x, NBKT - 1)], 1);
        atomicAdd(&lh[min(v.y, NBKT - 1)], 1);
        atomicAdd(&lh[min(v.z, NBKT - 1)], 1);
        atomicAdd(&lh[min(v.w, NBKT - 1)], 1);
    }
    __syncthreads();
    if (t < NBKT && lh[t]) atomicAdd(&gcount[t], lh[t]);
    if (t == 0) partials[b] = red[0];
}

// ---------------------------------------------------------------------------
// Scan phase 2 (single block, 1024 thr): scan partials -> blockoff + total;
// fused: heavy-first bucket offsets (gcur) + graph bounds binary search
// ---------------------------------------------------------------------------
__global__ void scan_mid_kernel(const int* __restrict__ partials,
                                int* __restrict__ blockoff,
                                int* __restrict__ rowptr,
                                const int* __restrict__ gcount,
                                int* __restrict__ gcur,
                                const int* __restrict__ batch,
                                int* __restrict__ grow) {
    __shared__ int sh[128];
    int t = threadIdx.x;
    int v = 0;
    if (t < 128) {
        v = (t < SCAN_NB) ? partials[t] : 0;
        sh[t] = v;
    }
    __syncthreads();
    for (int off = 1; off < 128; off <<= 1) {
        int u = 0;
        if (t < 128 && t >= off) u = sh[t - off];
        __syncthreads();
        if (t < 128) sh[t] += u;
        __syncthreads();
    }
    if (t < SCAN_NB) blockoff[t] = sh[t] - v;
    if (t == SCAN_NB - 1) rowptr[N_NODES] = sh[t];
    if (t == 0) {
        // heavy-first: descending bucket order so long blocks launch first
        int off = 0;
        for (int kk = NBKT - 1; kk >= 0; --kk) {
            gcur[kk] = off;
            off += (gcount[kk] + BPAD - 1) & ~(BPAD - 1);
        }
    }
    for (int gi = t; gi <= N_GRAPHS; gi += 1024) {
        if (gi == N_GRAPHS) { grow[gi] = N_NODES; continue; }
        int lo = 0, hi = N_NODES;
        while (lo < hi) { int mid = (lo + hi) >> 1; if (batch[mid] < gi) lo = mid + 1; else hi = mid; }
        grow[gi] = lo;
    }
}

// ---------------------------------------------------------------------------
// Scan phase 3: rowptr/cursor writeout + fused bucket scatter into nodelist
// ---------------------------------------------------------------------------
__global__ void scan_final_kernel(const int* __restrict__ deg,
                                  const int* __restrict__ blockoff,
                                  int* __restrict__ rowptr,
                                  int* __restrict__ cursor,
                                  int* __restrict__ gcur,
                                  int* __restrict__ nodelist) {
    __shared__ int sh[256];
    __shared__ int lh[NBKT], lbase[NBKT], lh2[NBKT];
    int b = blockIdx.x, t = threadIdx.x;
    if (t < NBKT) { lh[t] = 0; lh2[t] = 0; }
    int base = b * SCAN_CHUNK + t * 4;
    int4 v = make_int4(0, 0, 0, 0);
    if (base < N_NODES) v = *reinterpret_cast<const int4*>(deg + base);
    int s = v.x + v.y + v.z + v.w;
    sh[t] = s;
    __syncthreads();
    for (int off = 1; off < 256; off <<= 1) {
        int u = (t >= off) ? sh[t - off] : 0;
        __syncthreads();
        sh[t] += u;
        __syncthreads();
    }
    int k0 = min(v.x, NBKT - 1), k1 = min(v.y, NBKT - 1);
    int k2 = min(v.z, NBKT - 1), k3 = min(v.w, NBKT - 1);
    if (base < N_NODES) {
        int p0 = sh[t] - s + blockoff[b];
        int p1 = p0 + v.x, p2 = p1 + v.y, p3 = p2 + v.z;
        int4 pr = make_int4(p0, p1, p2, p3);
        *reinterpret_cast<int4*>(rowptr + base) = pr;
        *reinterpret_cast<int4*>(cursor + base) = pr;
        atomicAdd(&lh[k0], 1);
        atomicAdd(&lh[k1], 1);
        atomicAdd(&lh[k2], 1);
        atomicAdd(&lh[k3], 1);
    }
    __syncthreads();
    if (t < NBKT && lh[t]) lbase[t] = atomicAdd(&gcur[t], lh[t]);
    __syncthreads();
    if (base < N_NODES) {
        int r0 = atomicAdd(&lh2[k0], 1);
        nodelist[lbase[k0] + r0] = base + 0;
        int r1 = atomicAdd(&lh2[k1], 1);
        nodelist[lbase[k1] + r1] = base + 1;
        int r2 = atomicAdd(&lh2[k2], 1);
        nodelist[lbase[k2] + r2] = base + 2;
        int r3 = atomicAdd(&lh2[k3], 1);
        nodelist[lbase[k3] + r3] = base + 3;
    }
}

// ---------------------------------------------------------------------------
// Bin edges: csr[pos] = src
// ---------------------------------------------------------------------------
__global__ void fill_csr_kernel(const int* __restrict__ src, const int* __restrict__ dst,
                                int* __restrict__ cursor, int* __restrict__ csr) {
    int e = blockIdx.x * blockDim.x + threadIdx.x;
    if (e < N_EDGES) {
        int p = atomicAdd(&cursor[dst[e]], 1);
        csr[p] = src[e];
    }
}

// ---------------------------------------------------------------------------
// f32 -> bf16 row conversion
// ---------------------------------------------------------------------------
__global__ void f32_to_bf16_kernel(const float* __restrict__ in,
                                   unsigned short* __restrict__ out) {
    int i = (blockIdx.x * blockDim.x + threadIdx.x) * 4;
    if (i < N_NODES * DIM) {
        float4 v = *reinterpret_cast<const float4*>(in + i);
        ushort4 o;
        o.x = f2bf(v.x); o.y = f2bf(v.y); o.z = f2bf(v.z); o.w = f2bf(v.w);
        *reinterpret_cast<ushort4*>(out + i) = o;
    }
}

// ---------------------------------------------------------------------------
// Bucketed fused gather(bf16) + MFConv. (unchanged from R6)
// ---------------------------------------------------------------------------
template <int OUTMODE>
__global__ __launch_bounds__(256) void conv_bf16_kernel(
        const unsigned short* __restrict__ xbf,
        const int* __restrict__ rowptr,
        const int* __restrict__ csr,
        const int* __restrict__ nodelist,
        const float* __restrict__ Wl,
        const float* __restrict__ bl,
        const float* __restrict__ Wr,
        float* __restrict__ outf,
        unsigned short* __restrict__ outb) {
    __shared__ float lds_h[BPAD][DIM + 4];
    __shared__ float lds_x[BPAD][DIM + 4];
    __shared__ int s_node[BPAD];
    __shared__ int s_d0;

    int base = blockIdx.x * BPAD;
    int node0 = nodelist[base];
    if (node0 < 0) return;

    int grp = threadIdx.x >> 3;
    int q   = threadIdx.x & 7;
    int node = nodelist[base + grp];
    bool valid = (node >= 0);

    int beg = 0, end = 0;
    if (valid) { beg = rowptr[node]; end = rowptr[node + 1]; }

    if (threadIdx.x == 0) s_d0 = min(end - beg, MAXD);
    if (q == 0) s_node[grp] = node;

    float hs[8];
#pragma unroll
    for (int j = 0; j < 8; ++j) hs[j] = 0.f;

    int e = beg;
    for (; e + 8 <= end; e += 8) {
        int s0 = csr[e + 0], s1 = csr[e + 1], s2 = csr[e + 2], s3 = csr[e + 3];
        int s4 = csr[e + 4], s5 = csr[e + 5], s6 = csr[e + 6], s7 = csr[e + 7];
        int4 a0 = *reinterpret_cast<const int4*>(xbf + (size_t)s0 * DIM + q * 8);
        int4 a1 = *reinterpret_cast<const int4*>(xbf + (size_t)s1 * DIM + q * 8);
        int4 a2 = *reinterpret_cast<const int4*>(xbf + (size_t)s2 * DIM + q * 8);
        int4 a3 = *reinterpret_cast<const int4*>(xbf + (size_t)s3 * DIM + q * 8);
        int4 a4 = *reinterpret_cast<const int4*>(xbf + (size_t)s4 * DIM + q * 8);
        int4 a5 = *reinterpret_cast<const int4*>(xbf + (size_t)s5 * DIM + q * 8);
        int4 a6 = *reinterpret_cast<const int4*>(xbf + (size_t)s6 * DIM + q * 8);
        int4 a7 = *reinterpret_cast<const int4*>(xbf + (size_t)s7 * DIM + q * 8);
#define BFACC(a) \
        hs[0] += bflo(a.x); hs[1] += bfhi(a.x); \
        hs[2] += bflo(a.y); hs[3] += bfhi(a.y); \
        hs[4] += bflo(a.z); hs[5] += bfhi(a.z); \
        hs[6] += bflo(a.w); hs[7] += bfhi(a.w);
        BFACC(a0) BFACC(a1) BFACC(a2) BFACC(a3)
        BFACC(a4) BFACC(a5) BFACC(a6) BFACC(a7)
    }
    for (; e + 4 <= end; e += 4) {
        int s0 = csr[e + 0], s1 = csr[e + 1], s2 = csr[e + 2], s3 = csr[e + 3];
        int4 a0 = *reinterpret_cast<const int4*>(xbf + (size_t)s0 * DIM + q * 8);
        int4 a1 = *reinterpret_cast<const int4*>(xbf + (size_t)s1 * DIM + q * 8);
        int4 a2 = *reinterpret_cast<const int4*>(xbf + (size_t)s2 * DIM + q * 8);
        int4 a3 = *reinterpret_cast<const int4*>(xbf + (size_t)s3 * DIM + q * 8);
        BFACC(a0) BFACC(a1) BFACC(a2) BFACC(a3)
    }
    for (; e < end; ++e) {
        int s = csr[e];
        int4 a = *reinterpret_cast<const int4*>(xbf + (size_t)s * DIM + q * 8);
        BFACC(a)
    }
#undef BFACC

    float xv[8];
    if (valid) {
        int4 a = *reinterpret_cast<const int4*>(xbf + (size_t)node * DIM + q * 8);
        xv[0] = bflo(a.x); xv[1] = bfhi(a.x);
        xv[2] = bflo(a.y); xv[3] = bfhi(a.y);
        xv[4] = bflo(a.z); xv[5] = bfhi(a.z);
        xv[6] = bflo(a.w); xv[7] = bfhi(a.w);
    } else {
#pragma unroll
        for (int j = 0; j < 8; ++j) xv[j] = 0.f;
    }

    *reinterpret_cast<float4*>(&lds_h[grp][q * 8 + 0]) = make_float4(hs[0], hs[1], hs[2], hs[3]);
    *reinterpret_cast<float4*>(&lds_h[grp][q * 8 + 4]) = make_float4(hs[4], hs[5], hs[6], hs[7]);
    *reinterpret_cast<float4*>(&lds_x[grp][q * 8 + 0]) = make_float4(xv[0], xv[1], xv[2], xv[3]);
    *reinterpret_cast<float4*>(&lds_x[grp][q * 8 + 4]) = make_float4(xv[4], xv[5], xv[6], xv[7]);
    __syncthreads();

    int mgrp = threadIdx.x >> 4;
    int mq   = threadIdx.x & 15;
    int d0 = s_d0;
    const float* wl = Wl + (size_t)d0 * DIM * DIM + mq * 4;
    const float* wr = Wr + (size_t)d0 * DIM * DIM + mq * 4;
    float4 accA = *reinterpret_cast<const float4*>(bl + d0 * DIM + mq * 4);
    float4 accB = accA;

#pragma unroll 8
    for (int i = 0; i < DIM; ++i) {
        float4 wlv = *reinterpret_cast<const float4*>(wl + i * DIM);
        float4 wrv = *reinterpret_cast<const float4*>(wr + i * DIM);
        float hA = lds_h[mgrp][i],      xA = lds_x[mgrp][i];
        float hB = lds_h[mgrp + 16][i], xB = lds_x[mgrp + 16][i];
        accA.x += hA * wlv.x + xA * wrv.x;
        accA.y += hA * wlv.y + xA * wrv.y;
        accA.z += hA * wlv.z + xA * wrv.z;
        accA.w += hA * wlv.w + xA * wrv.w;
        accB.x += hB * wlv.x + xB * wrv.x;
        accB.y += hB * wlv.y + xB * wrv.y;
        accB.z += hB * wlv.z + xB * wrv.z;
        accB.w += hB * wlv.w + xB * wrv.w;
    }

    int nodeA = s_node[mgrp];
    int nodeB = s_node[mgrp + 16];
    if (OUTMODE == 0) {
        if (nodeA >= 0)
            *reinterpret_cast<float4*>(outf + (size_t)nodeA * DIM + mq * 4) = accA;
        if (nodeB >= 0)
            *reinterpret_cast<float4*>(outf + (size_t)nodeB * DIM + mq * 4) = accB;
    } else {
        if (nodeA >= 0) {
            ushort4 o;
            o.x = f2bf(fmaxf(accA.x, 0.f)); o.y = f2bf(fmaxf(accA.y, 0.f));
            o.z = f2bf(fmaxf(accA.z, 0.f)); o.w = f2bf(fmaxf(accA.w, 0.f));
            *reinterpret_cast<ushort4*>(outb + (size_t)nodeA * DIM + mq * 4) = o;
        }
        if (nodeB >= 0) {
            ushort4 o;
            o.x = f2bf(fmaxf(accB.x, 0.f)); o.y = f2bf(fmaxf(accB.y, 0.f));
            o.z = f2bf(fmaxf(accB.z, 0.f)); o.w = f2bf(fmaxf(accB.w, 0.f));
            *reinterpret_cast<ushort4*>(outb + (size_t)nodeB * DIM + mq * 4) = o;
        }
    }
}

// ---------------------------------------------------------------------------
// global_add_pool of relu(emb)
// ---------------------------------------------------------------------------
__global__ void pool_kernel(const float* __restrict__ emb,
                            const int* __restrict__ grow,
                            float* __restrict__ g) {
    __shared__ float red[4][DIM];
    int gi = blockIdx.x;
    int w = threadIdx.x >> 6;
    int lane = threadIdx.x & 63;
    int beg = grow[gi], end = grow[gi + 1];
    float acc = 0.f;
    for (int n = beg + w; n < end; n += 4)
        acc += fmaxf(emb[(size_t)n * DIM + lane], 0.f);
    red[w][lane] = acc;
    __syncthreads();
    if (w == 0) {
        g[(size_t)gi * DIM + lane] = red[0][lane] + red[1][lane] + red[2][lane] + red[3][lane];
    }
}

// ---------------------------------------------------------------------------
// Head
// ---------------------------------------------------------------------------
__global__ void head_kernel(const float* __restrict__ g,
                            const float* __restrict__ W1,
                            const float* __restrict__ b1,
                            const float* __restrict__ W2,
                            const float* __restrict__ b2,
                            float* __restrict__ pred) {
    __shared__ float hid[DIM];
    int gi = blockIdx.x;
    int o = threadIdx.x;
    const float* gv = g + (size_t)gi * DIM;
    float acc = b1[o];
#pragma unroll 8
    for (int i = 0; i < DIM; ++i) acc += gv[i] * W1[i * DIM + o];
    hid[o] = acc;
    __syncthreads();
    if (o < ODIM) {
        float p = b2[o];
#pragma unroll 8
        for (int i = 0; i < DIM; ++i) p += hid[i] * W2[i * ODIM + o];
        pred[(size_t)gi * ODIM + o] = p;
    }
}

extern "C" void kernel_launch(void* const* d_in, const int* in_sizes, int n_in,
                              void* d_out, int out_size, void* d_ws, size_t ws_size,
                              hipStream_t stream) {
    const float* x    = (const float*)d_in[0];
    const int* eidx   = (const int*)d_in[1];
    const int* src    = eidx;
    const int* dst    = eidx + N_EDGES;
    const int* batch  = (const int*)d_in[2];
    const float* Wl1  = (const float*)d_in[4];
    const float* bl1  = (const float*)d_in[5];
    const float* Wr1  = (const float*)d_in[6];
    const float* Wl2  = (const float*)d_in[7];
    const float* bl2  = (const float*)d_in[8];
    const float* Wr2  = (const float*)d_in[9];
    const float* W1   = (const float*)d_in[10];
    const float* b1   = (const float*)d_in[11];
    const float* W2   = (const float*)d_in[12];
    const float* b2   = (const float*)d_in[13];

    float* emb  = (float*)d_out;                          // [N_NODES, 64]
    float* pred = (float*)d_out + (size_t)N_NODES * DIM;  // [N_GRAPHS, 32]

    // Workspace layout (int counts all multiples of 4 -> 16B alignment kept)
    int* deg      = (int*)d_ws;                  // [100000]
    int* rowptr   = deg + N_NODES;               // [100004]
    int* cursor   = rowptr + N_NODES + 4;        // [100000]
    int* csr      = cursor + N_NODES;            // [1200000]
    int* grow     = csr + N_EDGES;               // [1004]
    int* partials = grow + 1004;                 // [100]
    int* blockoff = partials + 100;              // [100]
    int* gcount   = blockoff + 100;              // [32]
    int* gcur     = gcount + NBKT;               // [32]
    int* nodelist = gcur + NBKT;                 // [100992]
    unsigned short* xbf = (unsigned short*)(nodelist + LIST_PAD);  // [N*64] bf16
    unsigned short* hbf = xbf + (size_t)N_NODES * DIM;             // [N*64] bf16
    float* g = (float*)(hbf + (size_t)N_NODES * DIM);              // [G,64]

    init_kernel<<<(LIST_PAD + 255) / 256, 256, 0, stream>>>(deg, gcount, nodelist);
    deg_hist_kernel<<<(N_EDGES + 255) / 256, 256, 0, stream>>>(dst, deg);
    scan_partial_kernel<<<SCAN_NB, 256, 0, stream>>>(deg, partials, gcount);
    scan_mid_kernel<<<1, 1024, 0, stream>>>(partials, blockoff, rowptr, gcount,
                                            gcur, batch, grow);
    scan_final_kernel<<<SCAN_NB, 256, 0, stream>>>(deg, blockoff, rowptr, cursor,
                                                   gcur, nodelist);
    fill_csr_kernel<<<(N_EDGES + 255) / 256, 256, 0, stream>>>(src, dst, cursor, csr);
    f32_to_bf16_kernel<<<(N_NODES * DIM / 4 + 255) / 256, 256, 0, stream>>>(x, xbf);

    // conv1: bf16 gather + matvec + relu -> hbf
    conv_bf16_kernel<1><<<CONV_BLK, 256, 0, stream>>>(xbf, rowptr, csr, nodelist,
                                                      Wl1, bl1, Wr1, nullptr, hbf);
    // conv2: bf16 gather + matvec -> emb (f32, pre-activation output)
    conv_bf16_kernel<0><<<CONV_BLK, 256, 0, stream>>>(hbf, rowptr, csr, nodelist,
                                                      Wl2, bl2, Wr2, emb, nullptr);
    // pool relu(emb) per graph
    pool_kernel<<<N_GRAPHS, 256, 0, stream>>>(emb, grow, g);
    // head
    head_kernel<<<N_GRAPHS, DIM, 0, stream>>>(g, W1, b1, W2, b2, pred);
}